// Round 2
// baseline (302.120 us; speedup 1.0000x reference)
//
#include <hip/hip_runtime.h>
#include <hip/hip_bf16.h>

// Problem constants (fixed by reference): T=1024 tokens, H=1024, F=512, E=16,
// top-4 of 16 experts, group logic 4 groups of 4, scaling 2.5.
#define T_TOK 1024
#define H_DIM 1024
#define F_DIM 512
#define E_NUM 16

typedef short s16x8 __attribute__((ext_vector_type(8)));
typedef float fx4 __attribute__((ext_vector_type(4)));

__device__ __forceinline__ unsigned short f2bf(float f) {
  union { float f; unsigned u; } v; v.f = f;
  unsigned r = v.u + 0x7fffu + ((v.u >> 16) & 1u);
  return (unsigned short)(r >> 16);
}

// MFMA via inline asm: D(+=)A*B, 16x16x32 bf16. A: row=lane&15, k=(lane>>4)*8+j.
// B: col=lane&15, k=(lane>>4)*8+j. D: col=lane&15, row=(lane>>4)*4+r.
#define MFMA16(acc, a, b) \
  asm("v_mfma_f32_16x16x32_bf16 %0, %1, %2, %0" : "+v"(acc) : "v"(a), "v"(b))

#define GLOAD_LDS(gsrc, ldst)                                                  \
  __builtin_amdgcn_global_load_lds(                                            \
      (const __attribute__((address_space(1))) void*)(gsrc),                   \
      (__attribute__((address_space(3))) void*)(ldst), 16, 0, 0)

// ---------------------------------------------------------------- convert x
__global__ __launch_bounds__(256) void k_cvt_x(const float* __restrict__ in,
                                               unsigned short* __restrict__ out,
                                               int n4, int* __restrict__ meta) {
  if (blockIdx.x == 0 && threadIdx.x < 16) meta[threadIdx.x] = 0;  // zero counts
  int i = blockIdx.x * 256 + threadIdx.x;
  int stride = gridDim.x * 256;
  for (; i < n4; i += stride) {
    float4 v = ((const float4*)in)[i];
    ushort4 o;
    o.x = f2bf(v.x); o.y = f2bf(v.y); o.z = f2bf(v.z); o.w = f2bf(v.w);
    ((ushort4*)out)[i] = o;
  }
}

// ------------------------------------------- transpose+convert W fp32->bf16
// in: [E][R][C] fp32  ->  out: [E][C][R] bf16
__global__ __launch_bounds__(256) void k_trans(const float* __restrict__ in,
                                               unsigned short* __restrict__ out,
                                               int R, int C) {
  int e = blockIdx.z;
  int c0 = blockIdx.x * 64;
  int r0 = blockIdx.y * 64;
  const float* ip = in + (size_t)e * R * C;
  unsigned short* op = out + (size_t)e * R * C;
  __shared__ unsigned short tile[64][72];
  int tid = threadIdx.x;
  int cq = (tid & 15) * 4;
  int rr = tid >> 4;  // 0..15
#pragma unroll
  for (int p = 0; p < 4; ++p) {
    int r = rr + p * 16;
    float4 v = *(const float4*)(ip + (size_t)(r0 + r) * C + c0 + cq);
    tile[cq + 0][r] = f2bf(v.x);
    tile[cq + 1][r] = f2bf(v.y);
    tile[cq + 2][r] = f2bf(v.z);
    tile[cq + 3][r] = f2bf(v.w);
  }
  __syncthreads();
  int cr = tid >> 2;          // 0..63 output row within tile
  int rc = (tid & 3) * 16;    // 16-elem chunk
  unsigned short* dst = op + (size_t)(c0 + cr) * R + r0 + rc;
  *(uint4*)(dst + 0) = *(const uint4*)&tile[cr][rc + 0];
  *(uint4*)(dst + 8) = *(const uint4*)&tile[cr][rc + 8];
}

// ------------------------------------------------------------------ routing
__global__ __launch_bounds__(256) void k_route(const float* __restrict__ x,
                                               const float* __restrict__ gate,
                                               const float* __restrict__ ebias,
                                               int* __restrict__ counts,
                                               int* __restrict__ topk_e,
                                               float* __restrict__ topk_w) {
  int wave = threadIdx.x >> 6, lane = threadIdx.x & 63;
  int t = blockIdx.x * 4 + wave;
  const float* xr = x + (size_t)t * H_DIM;
  float acc[E_NUM];
#pragma unroll
  for (int e = 0; e < E_NUM; ++e) acc[e] = 0.f;
  for (int h0 = lane * 4; h0 < H_DIM; h0 += 256) {
    float4 xv = *(const float4*)(xr + h0);
    float xs[4] = {xv.x, xv.y, xv.z, xv.w};
#pragma unroll
    for (int j = 0; j < 4; ++j) {
      const float4* gr = (const float4*)(gate + (size_t)(h0 + j) * E_NUM);
      float4 g0 = gr[0], g1 = gr[1], g2 = gr[2], g3 = gr[3];
      float s = xs[j];
      acc[0] += s * g0.x;  acc[1] += s * g0.y;  acc[2] += s * g0.z;  acc[3] += s * g0.w;
      acc[4] += s * g1.x;  acc[5] += s * g1.y;  acc[6] += s * g1.z;  acc[7] += s * g1.w;
      acc[8] += s * g2.x;  acc[9] += s * g2.y;  acc[10] += s * g2.z; acc[11] += s * g2.w;
      acc[12] += s * g3.x; acc[13] += s * g3.y; acc[14] += s * g3.z; acc[15] += s * g3.w;
    }
  }
#pragma unroll
  for (int s = 1; s < 64; s <<= 1) {
#pragma unroll
    for (int e = 0; e < E_NUM; ++e) acc[e] += __shfl_xor(acc[e], s, 64);
  }
  float score[E_NUM], sfc[E_NUM];
#pragma unroll
  for (int e = 0; e < E_NUM; ++e) {
    score[e] = 1.f / (1.f + expf(-acc[e]));
    sfc[e] = score[e] + ebias[e];
  }
  // group scores: sum of top-2 within each group of 4
  float gs[4];
#pragma unroll
  for (int g = 0; g < 4; ++g) {
    float a = sfc[4 * g], b = sfc[4 * g + 1], c = sfc[4 * g + 2], d = sfc[4 * g + 3];
    float p = fmaxf(a, b), q = fminf(a, b), r2 = fmaxf(c, d), s2 = fminf(c, d);
    gs[g] = fmaxf(p, r2) + fmaxf(fminf(p, r2), fmaxf(q, s2));
  }
  int g1 = 0; float b1 = gs[0];
#pragma unroll
  for (int g = 1; g < 4; ++g) if (gs[g] > b1) { b1 = gs[g]; g1 = g; }
  int g2 = -1; float b2 = -1e30f;
#pragma unroll
  for (int g = 0; g < 4; ++g) {
    bool ok = (g != g1) && (gs[g] > b2);
    b2 = ok ? gs[g] : b2; g2 = ok ? g : g2;
  }
  // masked top-4 (masked-out groups contribute exactly 0.0, ties -> lower idx)
  unsigned sel = 0; int idx[4]; float w[4];
#pragma unroll
  for (int k = 0; k < 4; ++k) {
    float best = -1e30f; int bi = 0; float bw = 0.f;
#pragma unroll
    for (int ee = 0; ee < 16; ++ee) {
      int grp = ee >> 2;
      float v = (grp == g1 || grp == g2) ? sfc[ee] : 0.0f;
      bool ok = (((sel >> ee) & 1u) == 0u) && (v > best);
      best = ok ? v : best; bi = ok ? ee : bi; bw = ok ? score[ee] : bw;
    }
    sel |= (1u << bi); idx[k] = bi; w[k] = bw;
  }
  float sum = w[0] + w[1] + w[2] + w[3];
  float sc = 2.5f / (sum + 1e-20f);
  if (lane == 0) {
#pragma unroll
    for (int k = 0; k < 4; ++k) {
      topk_e[t * 4 + k] = idx[k];
      topk_w[t * 4 + k] = w[k] * sc;
      atomicAdd(&counts[idx[k]], 1);
    }
  }
}

// --------------------------------------------------------------- scan/scatter
__global__ void k_scan(const int* __restrict__ counts, int* __restrict__ cursors,
                       int* __restrict__ offsets) {
  if (threadIdx.x == 0) {
    int s = 0;
    for (int e = 0; e < E_NUM; ++e) { offsets[e] = s; cursors[e] = s; s += counts[e]; }
    offsets[E_NUM] = s;
  }
}

__global__ void k_scatter(const int* __restrict__ topk_e, const float* __restrict__ topk_w,
                          int* __restrict__ cursors, int* __restrict__ row_token,
                          float* __restrict__ row_w) {
  int i = blockIdx.x * 256 + threadIdx.x;  // 0..4095
  int e = topk_e[i];
  int slot = atomicAdd(&cursors[e], 1);
  row_token[slot] = i >> 2;
  row_w[slot] = topk_w[i];
}

// -------------------------------------------------------------------- GEMM1
// a_compact[slot][f] = silu(x.Wg)*(x.Wu)*w  (bf16), gathered rows per expert.
__global__ __launch_bounds__(256) void k_gemm1(
    const unsigned short* __restrict__ xb,    // [T][H] bf16
    const unsigned short* __restrict__ WgT,   // [E][F][H] bf16 (K-contig)
    const unsigned short* __restrict__ WuT,   // [E][F][H]
    const int* __restrict__ offsets, const int* __restrict__ row_token,
    const float* __restrict__ row_w,
    unsigned short* __restrict__ a_out) {     // [4096][F]
  int e = blockIdx.z;
  int offe = offsets[e];
  int ne = offsets[e + 1] - offe;
  int m0 = blockIdx.x * 64;
  if (m0 >= ne) return;
  int f0 = blockIdx.y * 64;

  __shared__ __align__(16) unsigned short As[4096];
  __shared__ __align__(16) unsigned short Bg[4096];
  __shared__ __align__(16) unsigned short Bu[4096];

  int tid = threadIdx.x;
  int wave = tid >> 6, lane = tid & 63;
  int wm = wave >> 1, wn = wave & 1;

  // staging: wave stages chunks ci=wave*2+i (1KB each: 8 rows x 128B).
  // XOR-swizzled source so linear global_load_lds dest + swizzled ds_read works.
  const unsigned short *sA[2], *sG[2], *sU[2];
  unsigned short *dA[2], *dG[2], *dU[2];
#pragma unroll
  for (int i = 0; i < 2; ++i) {
    int ci = wave * 2 + i;
    int r = ci * 8 + (lane >> 3);
    int sw = (lane & 7) ^ (r & 7);
    int slot = offe + m0 + r; if (slot > 4095) slot = 4095;
    int tok = row_token[slot];
    sA[i] = xb + (size_t)tok * H_DIM + sw * 8;
    sG[i] = WgT + ((size_t)e * F_DIM + f0 + r) * H_DIM + sw * 8;
    sU[i] = WuT + ((size_t)e * F_DIM + f0 + r) * H_DIM + sw * 8;
    dA[i] = As + ci * 512;
    dG[i] = Bg + ci * 512;
    dU[i] = Bu + ci * 512;
  }

  int offA[2][2], offB[2][2];
#pragma unroll
  for (int fm = 0; fm < 2; ++fm) {
    int row = wm * 32 + fm * 16 + (lane & 15);
#pragma unroll
    for (int kk = 0; kk < 2; ++kk)
      offA[fm][kk] = row * 64 + (((kk * 4 + (lane >> 4)) ^ (row & 7)) * 8);
  }
#pragma unroll
  for (int fn = 0; fn < 2; ++fn) {
    int row = wn * 32 + fn * 16 + (lane & 15);
#pragma unroll
    for (int kk = 0; kk < 2; ++kk)
      offB[fn][kk] = row * 64 + (((kk * 4 + (lane >> 4)) ^ (row & 7)) * 8);
  }

  fx4 ag[2][2] = {}; fx4 au[2][2] = {};

  for (int k0 = 0; k0 < H_DIM; k0 += 64) {
#pragma unroll
    for (int i = 0; i < 2; ++i) {
      GLOAD_LDS(sA[i] + k0, dA[i]);
      GLOAD_LDS(sG[i] + k0, dG[i]);
      GLOAD_LDS(sU[i] + k0, dU[i]);
    }
    __syncthreads();
#pragma unroll
    for (int kk = 0; kk < 2; ++kk) {
      s16x8 a0 = *(const s16x8*)(As + offA[0][kk]);
      s16x8 a1 = *(const s16x8*)(As + offA[1][kk]);
      s16x8 g0 = *(const s16x8*)(Bg + offB[0][kk]);
      s16x8 g1 = *(const s16x8*)(Bg + offB[1][kk]);
      s16x8 u0 = *(const s16x8*)(Bu + offB[0][kk]);
      s16x8 u1 = *(const s16x8*)(Bu + offB[1][kk]);
      MFMA16(ag[0][0], a0, g0); MFMA16(ag[0][1], a0, g1);
      MFMA16(ag[1][0], a1, g0); MFMA16(ag[1][1], a1, g1);
      MFMA16(au[0][0], a0, u0); MFMA16(au[0][1], a0, u1);
      MFMA16(au[1][0], a1, u0); MFMA16(au[1][1], a1, u1);
    }
    __syncthreads();
  }

#pragma unroll
  for (int fm = 0; fm < 2; ++fm) {
#pragma unroll
    for (int r = 0; r < 4; ++r) {
      int m = wm * 32 + fm * 16 + (lane >> 4) * 4 + r;
      bool ok = (m0 + m) < ne;
      int slot = offe + m0 + m;
      float w = ok ? row_w[slot] : 0.f;
#pragma unroll
      for (int fn = 0; fn < 2; ++fn) {
        int n = f0 + wn * 32 + fn * 16 + (lane & 15);
        float g = ag[fm][fn][r], u = au[fm][fn][r];
        float a = g / (1.f + __expf(-g)) * u * w;
        if (ok) a_out[(size_t)slot * F_DIM + n] = f2bf(a);
      }
    }
  }
}

// -------------------------------------------------------------------- GEMM2
// out[tok][h] += a_compact[slot] . WdT[e][h][:]   (atomicAdd combine)
__global__ __launch_bounds__(256) void k_gemm2(
    const unsigned short* __restrict__ a_in,  // [4096][F] bf16
    const unsigned short* __restrict__ WdT,   // [E][H][F] bf16 (K-contig)
    const int* __restrict__ offsets, const int* __restrict__ row_token,
    float* __restrict__ out) {                // [T][H] f32 (pre-zeroed)
  int e = blockIdx.z;
  int offe = offsets[e];
  int ne = offsets[e + 1] - offe;
  int m0 = blockIdx.x * 64;
  if (m0 >= ne) return;
  int h0 = blockIdx.y * 64;

  __shared__ __align__(16) unsigned short As[4096];
  __shared__ __align__(16) unsigned short Bd[4096];

  int tid = threadIdx.x;
  int wave = tid >> 6, lane = tid & 63;
  int wm = wave >> 1, wn = wave & 1;

  const unsigned short *sA[2], *sB[2];
  unsigned short *dA[2], *dB[2];
#pragma unroll
  for (int i = 0; i < 2; ++i) {
    int ci = wave * 2 + i;
    int r = ci * 8 + (lane >> 3);
    int sw = (lane & 7) ^ (r & 7);
    int slot = offe + m0 + r; if (slot > 4095) slot = 4095;
    sA[i] = a_in + (size_t)slot * F_DIM + sw * 8;
    sB[i] = WdT + ((size_t)e * H_DIM + h0 + r) * F_DIM + sw * 8;
    dA[i] = As + ci * 512;
    dB[i] = Bd + ci * 512;
  }

  int offA[2][2], offB[2][2];
#pragma unroll
  for (int fm = 0; fm < 2; ++fm) {
    int row = wm * 32 + fm * 16 + (lane & 15);
#pragma unroll
    for (int kk = 0; kk < 2; ++kk)
      offA[fm][kk] = row * 64 + (((kk * 4 + (lane >> 4)) ^ (row & 7)) * 8);
  }
#pragma unroll
  for (int fn = 0; fn < 2; ++fn) {
    int row = wn * 32 + fn * 16 + (lane & 15);
#pragma unroll
    for (int kk = 0; kk < 2; ++kk)
      offB[fn][kk] = row * 64 + (((kk * 4 + (lane >> 4)) ^ (row & 7)) * 8);
  }

  fx4 acc[2][2] = {};

  for (int k0 = 0; k0 < F_DIM; k0 += 64) {
#pragma unroll
    for (int i = 0; i < 2; ++i) {
      GLOAD_LDS(sA[i] + k0, dA[i]);
      GLOAD_LDS(sB[i] + k0, dB[i]);
    }
    __syncthreads();
#pragma unroll
    for (int kk = 0; kk < 2; ++kk) {
      s16x8 a0 = *(const s16x8*)(As + offA[0][kk]);
      s16x8 a1 = *(const s16x8*)(As + offA[1][kk]);
      s16x8 b0 = *(const s16x8*)(Bd + offB[0][kk]);
      s16x8 b1 = *(const s16x8*)(Bd + offB[1][kk]);
      MFMA16(acc[0][0], a0, b0); MFMA16(acc[0][1], a0, b1);
      MFMA16(acc[1][0], a1, b0); MFMA16(acc[1][1], a1, b1);
    }
    __syncthreads();
  }

#pragma unroll
  for (int fm = 0; fm < 2; ++fm) {
#pragma unroll
    for (int r = 0; r < 4; ++r) {
      int m = wm * 32 + fm * 16 + (lane >> 4) * 4 + r;
      bool ok = (m0 + m) < ne;
      int slot = offe + m0 + m; if (slot > 4095) slot = 4095;
      int tok = row_token[slot];
#pragma unroll
      for (int fn = 0; fn < 2; ++fn) {
        int n = h0 + wn * 32 + fn * 16 + (lane & 15);
        if (ok) atomicAdd(out + (size_t)tok * H_DIM + n, acc[fm][fn][r]);
      }
    }
  }
}

// ------------------------------------------------------------------- launch
extern "C" void kernel_launch(void* const* d_in, const int* in_sizes, int n_in,
                              void* d_out, int out_size, void* d_ws, size_t ws_size,
                              hipStream_t stream) {
  (void)in_sizes; (void)n_in; (void)out_size; (void)ws_size;
  const float* x    = (const float*)d_in[0];
  const float* gate = (const float*)d_in[1];
  const float* eb   = (const float*)d_in[2];
  const float* Wg   = (const float*)d_in[3];
  const float* Wu   = (const float*)d_in[4];
  const float* Wd   = (const float*)d_in[5];
  float* out = (float*)d_out;
  char* ws = (char*)d_ws;

  int*   counts  = (int*)(ws + 0);
  int*   cursors = (int*)(ws + 256);
  int*   offsets = (int*)(ws + 512);
  int*   topk_e  = (int*)(ws + 4096);
  float* topk_w  = (float*)(ws + 4096 + 16384);
  int*   row_tok = (int*)(ws + 4096 + 2 * 16384);
  float* row_w   = (float*)(ws + 4096 + 3 * 16384);
  unsigned short* xb  = (unsigned short*)(ws + (size_t)(1u << 20));        // 2 MB
  unsigned short* ac  = (unsigned short*)(ws + (size_t)3 * (1u << 20));    // 4 MB
  unsigned short* WgT = (unsigned short*)(ws + (size_t)16 * (1u << 20));   // 16 MB
  unsigned short* WuT = (unsigned short*)(ws + (size_t)32 * (1u << 20));   // 16 MB
  unsigned short* WdT = (unsigned short*)(ws + (size_t)48 * (1u << 20));   // 16 MB

  hipMemsetAsync(d_out, 0, (size_t)T_TOK * H_DIM * sizeof(float), stream);
  k_cvt_x<<<1024, 256, 0, stream>>>(x, xb, (T_TOK * H_DIM) / 4, counts);
  k_trans<<<dim3(F_DIM / 64, H_DIM / 64, E_NUM), 256, 0, stream>>>(Wg, WgT, H_DIM, F_DIM);
  k_trans<<<dim3(F_DIM / 64, H_DIM / 64, E_NUM), 256, 0, stream>>>(Wu, WuT, H_DIM, F_DIM);
  k_trans<<<dim3(H_DIM / 64, F_DIM / 64, E_NUM), 256, 0, stream>>>(Wd, WdT, F_DIM, H_DIM);
  k_route<<<T_TOK / 4, 256, 0, stream>>>(x, gate, eb, counts, topk_e, topk_w);
  k_scan<<<1, 64, 0, stream>>>(counts, cursors, offsets);
  k_scatter<<<(T_TOK * 4) / 256, 256, 0, stream>>>(topk_e, topk_w, cursors, row_tok, row_w);
  k_gemm1<<<dim3(16, F_DIM / 64, E_NUM), 256, 0, stream>>>(xb, WgT, WuT, offsets, row_tok, row_w, ac);
  k_gemm2<<<dim3(16, H_DIM / 64, E_NUM), 256, 0, stream>>>(ac, WdT, offsets, row_tok, out);
}

// Round 3
// 256.344 us; speedup vs baseline: 1.1786x; 1.1786x over previous
//
#include <hip/hip_runtime.h>
#include <hip/hip_bf16.h>

// Problem constants (fixed by reference): T=1024 tokens, H=1024, F=512, E=16,
// top-4 of 16 experts, group logic 4 groups of 4, scaling 2.5.
#define T_TOK 1024
#define H_DIM 1024
#define F_DIM 512
#define E_NUM 16

typedef short s16x8 __attribute__((ext_vector_type(8)));
typedef float fx4 __attribute__((ext_vector_type(4)));

__device__ __forceinline__ unsigned short f2bf(float f) {
  union { float f; unsigned u; } v; v.f = f;
  unsigned r = v.u + 0x7fffu + ((v.u >> 16) & 1u);
  return (unsigned short)(r >> 16);
}

// MFMA via inline asm: D(+=)A*B, 16x16x32 bf16. A: row=lane&15, k=(lane>>4)*8+j.
// B: col=lane&15, k=(lane>>4)*8+j. D: col=lane&15, row=(lane>>4)*4+r.
#define MFMA16(acc, a, b) \
  asm("v_mfma_f32_16x16x32_bf16 %0, %1, %2, %0" : "+v"(acc) : "v"(a), "v"(b))

#define GLOAD_LDS(gsrc, ldst)                                                  \
  __builtin_amdgcn_global_load_lds(                                            \
      (const __attribute__((address_space(1))) void*)(gsrc),                   \
      (__attribute__((address_space(3))) void*)(ldst), 16, 0, 0)

// ---------------------------------------------------------------- convert x
__global__ __launch_bounds__(256) void k_cvt_x(const float* __restrict__ in,
                                               unsigned short* __restrict__ out,
                                               int n4) {
  int i = blockIdx.x * 256 + threadIdx.x;
  int stride = gridDim.x * 256;
  for (; i < n4; i += stride) {
    float4 v = ((const float4*)in)[i];
    ushort4 o;
    o.x = f2bf(v.x); o.y = f2bf(v.y); o.z = f2bf(v.z); o.w = f2bf(v.w);
    ((ushort4*)out)[i] = o;
  }
}

// ------------------------------------------- transpose+convert W fp32->bf16
// in: [E][R][C] fp32  ->  out: [E][C][R] bf16
__global__ __launch_bounds__(256) void k_trans(const float* __restrict__ in,
                                               unsigned short* __restrict__ out,
                                               int R, int C) {
  int e = blockIdx.z;
  int c0 = blockIdx.x * 64;
  int r0 = blockIdx.y * 64;
  const float* ip = in + (size_t)e * R * C;
  unsigned short* op = out + (size_t)e * R * C;
  __shared__ unsigned short tile[64][72];
  int tid = threadIdx.x;
  int cq = (tid & 15) * 4;
  int rr = tid >> 4;  // 0..15
#pragma unroll
  for (int p = 0; p < 4; ++p) {
    int r = rr + p * 16;
    float4 v = *(const float4*)(ip + (size_t)(r0 + r) * C + c0 + cq);
    tile[cq + 0][r] = f2bf(v.x);
    tile[cq + 1][r] = f2bf(v.y);
    tile[cq + 2][r] = f2bf(v.z);
    tile[cq + 3][r] = f2bf(v.w);
  }
  __syncthreads();
  int cr = tid >> 2;          // 0..63 output row within tile
  int rc = (tid & 3) * 16;    // 16-elem chunk
  unsigned short* dst = op + (size_t)(c0 + cr) * R + r0 + rc;
  *(uint4*)(dst + 0) = *(const uint4*)&tile[cr][rc + 0];
  *(uint4*)(dst + 8) = *(const uint4*)&tile[cr][rc + 8];
}

// ------------------------------------------------------------------ routing
// One wave per token. NO global atomics (the round-2 profile showed the
// 4096-atomic storm on one cache line cost ~58us of pure wait).
__global__ __launch_bounds__(256) void k_route(const float* __restrict__ x,
                                               const float* __restrict__ gate,
                                               const float* __restrict__ ebias,
                                               int* __restrict__ topk_e,
                                               float* __restrict__ topk_w) {
  int wave = threadIdx.x >> 6, lane = threadIdx.x & 63;
  int t = blockIdx.x * 4 + wave;
  const float* xr = x + (size_t)t * H_DIM;
  float acc[E_NUM];
#pragma unroll
  for (int e = 0; e < E_NUM; ++e) acc[e] = 0.f;
  for (int h0 = lane * 4; h0 < H_DIM; h0 += 256) {
    float4 xv = *(const float4*)(xr + h0);
    float xs[4] = {xv.x, xv.y, xv.z, xv.w};
#pragma unroll
    for (int j = 0; j < 4; ++j) {
      const float4* gr = (const float4*)(gate + (size_t)(h0 + j) * E_NUM);
      float4 g0 = gr[0], g1 = gr[1], g2 = gr[2], g3 = gr[3];
      float s = xs[j];
      acc[0] += s * g0.x;  acc[1] += s * g0.y;  acc[2] += s * g0.z;  acc[3] += s * g0.w;
      acc[4] += s * g1.x;  acc[5] += s * g1.y;  acc[6] += s * g1.z;  acc[7] += s * g1.w;
      acc[8] += s * g2.x;  acc[9] += s * g2.y;  acc[10] += s * g2.z; acc[11] += s * g2.w;
      acc[12] += s * g3.x; acc[13] += s * g3.y; acc[14] += s * g3.z; acc[15] += s * g3.w;
    }
  }
#pragma unroll
  for (int s = 1; s < 64; s <<= 1) {
#pragma unroll
    for (int e = 0; e < E_NUM; ++e) acc[e] += __shfl_xor(acc[e], s, 64);
  }
  float score[E_NUM], sfc[E_NUM];
#pragma unroll
  for (int e = 0; e < E_NUM; ++e) {
    score[e] = 1.f / (1.f + expf(-acc[e]));
    sfc[e] = score[e] + ebias[e];
  }
  // group scores: sum of top-2 within each group of 4
  float gs[4];
#pragma unroll
  for (int g = 0; g < 4; ++g) {
    float a = sfc[4 * g], b = sfc[4 * g + 1], c = sfc[4 * g + 2], d = sfc[4 * g + 3];
    float p = fmaxf(a, b), q = fminf(a, b), r2 = fmaxf(c, d), s2 = fminf(c, d);
    gs[g] = fmaxf(p, r2) + fmaxf(fminf(p, r2), fmaxf(q, s2));
  }
  int g1 = 0; float b1 = gs[0];
#pragma unroll
  for (int g = 1; g < 4; ++g) if (gs[g] > b1) { b1 = gs[g]; g1 = g; }
  int g2 = -1; float b2 = -1e30f;
#pragma unroll
  for (int g = 0; g < 4; ++g) {
    bool ok = (g != g1) && (gs[g] > b2);
    b2 = ok ? gs[g] : b2; g2 = ok ? g : g2;
  }
  // masked top-4 (masked-out groups contribute exactly 0.0, ties -> lower idx)
  unsigned sel = 0; int idx[4]; float w[4];
#pragma unroll
  for (int k = 0; k < 4; ++k) {
    float best = -1e30f; int bi = 0; float bw = 0.f;
#pragma unroll
    for (int ee = 0; ee < 16; ++ee) {
      int grp = ee >> 2;
      float v = (grp == g1 || grp == g2) ? sfc[ee] : 0.0f;
      bool ok = (((sel >> ee) & 1u) == 0u) && (v > best);
      best = ok ? v : best; bi = ok ? ee : bi; bw = ok ? score[ee] : bw;
    }
    sel |= (1u << bi); idx[k] = bi; w[k] = bw;
  }
  float sum = w[0] + w[1] + w[2] + w[3];
  float sc = 2.5f / (sum + 1e-20f);
  if (lane == 0) {
#pragma unroll
    for (int k = 0; k < 4; ++k) {
      topk_e[t * 4 + k] = idx[k];
      topk_w[t * 4 + k] = w[k] * sc;
    }
  }
}

// ------------------------------------- histogram + prefix + scatter (1 block)
// Replaces k_scan + k_scatter; all counting via LDS atomics (no cross-XCD
// cache-line ping-pong).
__global__ __launch_bounds__(256) void k_sort(const int* __restrict__ topk_e,
                                              const float* __restrict__ topk_w,
                                              int* __restrict__ offsets,
                                              int* __restrict__ row_token,
                                              float* __restrict__ row_w) {
  __shared__ int bins[E_NUM];
  __shared__ int base[E_NUM + 1];
  int tid = threadIdx.x;
  if (tid < E_NUM) bins[tid] = 0;
  __syncthreads();
  for (int i = tid; i < T_TOK * 4; i += 256) atomicAdd(&bins[topk_e[i]], 1);
  __syncthreads();
  if (tid == 0) {
    int s = 0;
    for (int k = 0; k < E_NUM; ++k) { base[k] = s; s += bins[k]; }
    base[E_NUM] = s;
  }
  __syncthreads();
  if (tid < E_NUM + 1) offsets[tid] = base[tid];
  if (tid < E_NUM) bins[tid] = base[tid];  // reuse as cursors
  __syncthreads();
  for (int i = tid; i < T_TOK * 4; i += 256) {
    int ee = topk_e[i];
    int slot = atomicAdd(&bins[ee], 1);
    row_token[slot] = i >> 2;
    row_w[slot] = topk_w[i];
  }
}

// -------------------------------------------------------------------- GEMM1
// a_compact[slot][f] = silu(x.Wg)*(x.Wu)*w  (bf16), gathered rows per expert.
__global__ __launch_bounds__(256) void k_gemm1(
    const unsigned short* __restrict__ xb,    // [T][H] bf16
    const unsigned short* __restrict__ WgT,   // [E][F][H] bf16 (K-contig)
    const unsigned short* __restrict__ WuT,   // [E][F][H]
    const int* __restrict__ offsets, const int* __restrict__ row_token,
    const float* __restrict__ row_w,
    unsigned short* __restrict__ a_out) {     // [4096][F]
  int e = blockIdx.z;
  int offe = offsets[e];
  int ne = offsets[e + 1] - offe;
  int m0 = blockIdx.x * 64;
  if (m0 >= ne) return;
  int f0 = blockIdx.y * 64;

  __shared__ __align__(16) unsigned short As[4096];
  __shared__ __align__(16) unsigned short Bg[4096];
  __shared__ __align__(16) unsigned short Bu[4096];

  int tid = threadIdx.x;
  int wave = tid >> 6, lane = tid & 63;
  int wm = wave >> 1, wn = wave & 1;

  // staging: wave stages chunks ci=wave*2+i (1KB each: 8 rows x 128B).
  // XOR-swizzled source so linear global_load_lds dest + swizzled ds_read works.
  const unsigned short *sA[2], *sG[2], *sU[2];
  unsigned short *dA[2], *dG[2], *dU[2];
#pragma unroll
  for (int i = 0; i < 2; ++i) {
    int ci = wave * 2 + i;
    int r = ci * 8 + (lane >> 3);
    int sw = (lane & 7) ^ (r & 7);
    int slot = offe + m0 + r; if (slot > 4095) slot = 4095;
    int tok = row_token[slot];
    sA[i] = xb + (size_t)tok * H_DIM + sw * 8;
    sG[i] = WgT + ((size_t)e * F_DIM + f0 + r) * H_DIM + sw * 8;
    sU[i] = WuT + ((size_t)e * F_DIM + f0 + r) * H_DIM + sw * 8;
    dA[i] = As + ci * 512;
    dG[i] = Bg + ci * 512;
    dU[i] = Bu + ci * 512;
  }

  int offA[2][2], offB[2][2];
#pragma unroll
  for (int fm = 0; fm < 2; ++fm) {
    int row = wm * 32 + fm * 16 + (lane & 15);
#pragma unroll
    for (int kk = 0; kk < 2; ++kk)
      offA[fm][kk] = row * 64 + (((kk * 4 + (lane >> 4)) ^ (row & 7)) * 8);
  }
#pragma unroll
  for (int fn = 0; fn < 2; ++fn) {
    int row = wn * 32 + fn * 16 + (lane & 15);
#pragma unroll
    for (int kk = 0; kk < 2; ++kk)
      offB[fn][kk] = row * 64 + (((kk * 4 + (lane >> 4)) ^ (row & 7)) * 8);
  }

  fx4 ag[2][2] = {}; fx4 au[2][2] = {};

  for (int k0 = 0; k0 < H_DIM; k0 += 64) {
#pragma unroll
    for (int i = 0; i < 2; ++i) {
      GLOAD_LDS(sA[i] + k0, dA[i]);
      GLOAD_LDS(sG[i] + k0, dG[i]);
      GLOAD_LDS(sU[i] + k0, dU[i]);
    }
    __syncthreads();
#pragma unroll
    for (int kk = 0; kk < 2; ++kk) {
      s16x8 a0 = *(const s16x8*)(As + offA[0][kk]);
      s16x8 a1 = *(const s16x8*)(As + offA[1][kk]);
      s16x8 g0 = *(const s16x8*)(Bg + offB[0][kk]);
      s16x8 g1 = *(const s16x8*)(Bg + offB[1][kk]);
      s16x8 u0 = *(const s16x8*)(Bu + offB[0][kk]);
      s16x8 u1 = *(const s16x8*)(Bu + offB[1][kk]);
      MFMA16(ag[0][0], a0, g0); MFMA16(ag[0][1], a0, g1);
      MFMA16(ag[1][0], a1, g0); MFMA16(ag[1][1], a1, g1);
      MFMA16(au[0][0], a0, u0); MFMA16(au[0][1], a0, u1);
      MFMA16(au[1][0], a1, u0); MFMA16(au[1][1], a1, u1);
    }
    __syncthreads();
  }

#pragma unroll
  for (int fm = 0; fm < 2; ++fm) {
#pragma unroll
    for (int r = 0; r < 4; ++r) {
      int m = wm * 32 + fm * 16 + (lane >> 4) * 4 + r;
      bool ok = (m0 + m) < ne;
      int slot = offe + m0 + m;
      float w = ok ? row_w[slot] : 0.f;
#pragma unroll
      for (int fn = 0; fn < 2; ++fn) {
        int n = f0 + wn * 32 + fn * 16 + (lane & 15);
        float g = ag[fm][fn][r], u = au[fm][fn][r];
        float a = g / (1.f + __expf(-g)) * u * w;
        if (ok) a_out[(size_t)slot * F_DIM + n] = f2bf(a);
      }
    }
  }
}

// -------------------------------------------------------------------- GEMM2
// out[tok][h] += a_compact[slot] . WdT[e][h][:]   (atomicAdd combine)
__global__ __launch_bounds__(256) void k_gemm2(
    const unsigned short* __restrict__ a_in,  // [4096][F] bf16
    const unsigned short* __restrict__ WdT,   // [E][H][F] bf16 (K-contig)
    const int* __restrict__ offsets, const int* __restrict__ row_token,
    float* __restrict__ out) {                // [T][H] f32 (pre-zeroed)
  int e = blockIdx.z;
  int offe = offsets[e];
  int ne = offsets[e + 1] - offe;
  int m0 = blockIdx.x * 64;
  if (m0 >= ne) return;
  int h0 = blockIdx.y * 64;

  __shared__ __align__(16) unsigned short As[4096];
  __shared__ __align__(16) unsigned short Bd[4096];

  int tid = threadIdx.x;
  int wave = tid >> 6, lane = tid & 63;
  int wm = wave >> 1, wn = wave & 1;

  const unsigned short *sA[2], *sB[2];
  unsigned short *dA[2], *dB[2];
#pragma unroll
  for (int i = 0; i < 2; ++i) {
    int ci = wave * 2 + i;
    int r = ci * 8 + (lane >> 3);
    int sw = (lane & 7) ^ (r & 7);
    int slot = offe + m0 + r; if (slot > 4095) slot = 4095;
    sA[i] = a_in + (size_t)slot * F_DIM + sw * 8;
    sB[i] = WdT + ((size_t)e * H_DIM + h0 + r) * F_DIM + sw * 8;
    dA[i] = As + ci * 512;
    dB[i] = Bd + ci * 512;
  }

  int offA[2][2], offB[2][2];
#pragma unroll
  for (int fm = 0; fm < 2; ++fm) {
    int row = wm * 32 + fm * 16 + (lane & 15);
#pragma unroll
    for (int kk = 0; kk < 2; ++kk)
      offA[fm][kk] = row * 64 + (((kk * 4 + (lane >> 4)) ^ (row & 7)) * 8);
  }
#pragma unroll
  for (int fn = 0; fn < 2; ++fn) {
    int row = wn * 32 + fn * 16 + (lane & 15);
#pragma unroll
    for (int kk = 0; kk < 2; ++kk)
      offB[fn][kk] = row * 64 + (((kk * 4 + (lane >> 4)) ^ (row & 7)) * 8);
  }

  fx4 acc[2][2] = {};

  for (int k0 = 0; k0 < F_DIM; k0 += 64) {
#pragma unroll
    for (int i = 0; i < 2; ++i) {
      GLOAD_LDS(sA[i] + k0, dA[i]);
      GLOAD_LDS(sB[i] + k0, dB[i]);
    }
    __syncthreads();
#pragma unroll
    for (int kk = 0; kk < 2; ++kk) {
      s16x8 a0 = *(const s16x8*)(As + offA[0][kk]);
      s16x8 a1 = *(const s16x8*)(As + offA[1][kk]);
      s16x8 b0 = *(const s16x8*)(Bd + offB[0][kk]);
      s16x8 b1 = *(const s16x8*)(Bd + offB[1][kk]);
      MFMA16(acc[0][0], a0, b0); MFMA16(acc[0][1], a0, b1);
      MFMA16(acc[1][0], a1, b0); MFMA16(acc[1][1], a1, b1);
    }
    __syncthreads();
  }

#pragma unroll
  for (int fm = 0; fm < 2; ++fm) {
#pragma unroll
    for (int r = 0; r < 4; ++r) {
      int m = wm * 32 + fm * 16 + (lane >> 4) * 4 + r;
      bool ok = (m0 + m) < ne;
      int slot = offe + m0 + m; if (slot > 4095) slot = 4095;
      int tok = row_token[slot];
#pragma unroll
      for (int fn = 0; fn < 2; ++fn) {
        int n = h0 + wn * 32 + fn * 16 + (lane & 15);
        if (ok) atomicAdd(out + (size_t)tok * H_DIM + n, acc[fm][fn][r]);
      }
    }
  }
}

// ------------------------------------------------------------------- launch
extern "C" void kernel_launch(void* const* d_in, const int* in_sizes, int n_in,
                              void* d_out, int out_size, void* d_ws, size_t ws_size,
                              hipStream_t stream) {
  (void)in_sizes; (void)n_in; (void)out_size; (void)ws_size;
  const float* x    = (const float*)d_in[0];
  const float* gate = (const float*)d_in[1];
  const float* eb   = (const float*)d_in[2];
  const float* Wg   = (const float*)d_in[3];
  const float* Wu   = (const float*)d_in[4];
  const float* Wd   = (const float*)d_in[5];
  float* out = (float*)d_out;
  char* ws = (char*)d_ws;

  int*   offsets = (int*)(ws + 512);
  int*   topk_e  = (int*)(ws + 4096);
  float* topk_w  = (float*)(ws + 4096 + 16384);
  int*   row_tok = (int*)(ws + 4096 + 2 * 16384);
  float* row_w   = (float*)(ws + 4096 + 3 * 16384);
  unsigned short* xb  = (unsigned short*)(ws + (size_t)(1u << 20));        // 2 MB
  unsigned short* ac  = (unsigned short*)(ws + (size_t)3 * (1u << 20));    // 4 MB
  unsigned short* WgT = (unsigned short*)(ws + (size_t)16 * (1u << 20));   // 16 MB
  unsigned short* WuT = (unsigned short*)(ws + (size_t)32 * (1u << 20));   // 16 MB
  unsigned short* WdT = (unsigned short*)(ws + (size_t)48 * (1u << 20));   // 16 MB

  hipMemsetAsync(d_out, 0, (size_t)T_TOK * H_DIM * sizeof(float), stream);
  k_cvt_x<<<1024, 256, 0, stream>>>(x, xb, (T_TOK * H_DIM) / 4);
  k_trans<<<dim3(F_DIM / 64, H_DIM / 64, E_NUM), 256, 0, stream>>>(Wg, WgT, H_DIM, F_DIM);
  k_trans<<<dim3(F_DIM / 64, H_DIM / 64, E_NUM), 256, 0, stream>>>(Wu, WuT, H_DIM, F_DIM);
  k_trans<<<dim3(H_DIM / 64, F_DIM / 64, E_NUM), 256, 0, stream>>>(Wd, WdT, F_DIM, H_DIM);
  k_route<<<T_TOK / 4, 256, 0, stream>>>(x, gate, eb, topk_e, topk_w);
  k_sort<<<1, 256, 0, stream>>>(topk_e, topk_w, offsets, row_tok, row_w);
  k_gemm1<<<dim3(16, F_DIM / 64, E_NUM), 256, 0, stream>>>(xb, WgT, WuT, offsets, row_tok, row_w, ac);
  k_gemm2<<<dim3(16, H_DIM / 64, E_NUM), 256, 0, stream>>>(ac, WdT, offsets, row_tok, out);
}

// Round 5
// 223.213 us; speedup vs baseline: 1.3535x; 1.1484x over previous
//
#include <hip/hip_runtime.h>
#include <hip/hip_bf16.h>

// Problem constants (fixed by reference): T=1024 tokens, H=1024, F=512, E=16,
// top-4 of 16 experts, group logic 4 groups of 4, scaling 2.5.
#define T_TOK 1024
#define H_DIM 1024
#define F_DIM 512
#define E_NUM 16

typedef short s16x8 __attribute__((ext_vector_type(8)));
typedef float fx4 __attribute__((ext_vector_type(4)));

__device__ __forceinline__ unsigned short f2bf(float f) {
  union { float f; unsigned u; } v; v.f = f;
  unsigned r = v.u + 0x7fffu + ((v.u >> 16) & 1u);
  return (unsigned short)(r >> 16);
}

// MFMA via inline asm: D(+=)A*B, 16x16x32 bf16. A: row=lane&15, k=(lane>>4)*8+j.
// B: col=lane&15, k=(lane>>4)*8+j. D: col=lane&15, row=(lane>>4)*4+r.
#define MFMA16(acc, a, b) \
  asm("v_mfma_f32_16x16x32_bf16 %0, %1, %2, %0" : "+v"(acc) : "v"(a), "v"(b))

#define GLOAD_LDS(gsrc, ldst)                                                  \
  __builtin_amdgcn_global_load_lds(                                            \
      (const __attribute__((address_space(1))) void*)(gsrc),                   \
      (__attribute__((address_space(3))) void*)(ldst), 16, 0, 0)

// ---------------------------------------------------------------- convert x
__global__ __launch_bounds__(256) void k_cvt_x(const float* __restrict__ in,
                                               unsigned short* __restrict__ out,
                                               int n4) {
  int i = blockIdx.x * 256 + threadIdx.x;
  int stride = gridDim.x * 256;
  for (; i < n4; i += stride) {
    float4 v = ((const float4*)in)[i];
    ushort4 o;
    o.x = f2bf(v.x); o.y = f2bf(v.y); o.z = f2bf(v.z); o.w = f2bf(v.w);
    ((ushort4*)out)[i] = o;
  }
}

// ------------------------------------------- transpose+convert W fp32->bf16
// in: [E][R][C] fp32  ->  out: [E][C][R] bf16
__global__ __launch_bounds__(256) void k_trans(const float* __restrict__ in,
                                               unsigned short* __restrict__ out,
                                               int R, int C) {
  int e = blockIdx.z;
  int c0 = blockIdx.x * 64;
  int r0 = blockIdx.y * 64;
  const float* ip = in + (size_t)e * R * C;
  unsigned short* op = out + (size_t)e * R * C;
  __shared__ unsigned short tile[64][72];
  int tid = threadIdx.x;
  int cq = (tid & 15) * 4;
  int rr = tid >> 4;  // 0..15
#pragma unroll
  for (int p = 0; p < 4; ++p) {
    int r = rr + p * 16;
    float4 v = *(const float4*)(ip + (size_t)(r0 + r) * C + c0 + cq);
    tile[cq + 0][r] = f2bf(v.x);
    tile[cq + 1][r] = f2bf(v.y);
    tile[cq + 2][r] = f2bf(v.z);
    tile[cq + 3][r] = f2bf(v.w);
  }
  __syncthreads();
  int cr = tid >> 2;          // 0..63 output row within tile
  int rc = (tid & 3) * 16;    // 16-elem chunk
  unsigned short* dst = op + (size_t)(c0 + cr) * R + r0 + rc;
  *(uint4*)(dst + 0) = *(const uint4*)&tile[cr][rc + 0];
  *(uint4*)(dst + 8) = *(const uint4*)&tile[cr][rc + 8];
}

// ------------------------------------------------------------------ routing
// One wave per token. NO global atomics (round-2 profile: 4096 atomics on one
// cache line cost ~58us of cross-XCD serialization).
__global__ __launch_bounds__(256) void k_route(const float* __restrict__ x,
                                               const float* __restrict__ gate,
                                               const float* __restrict__ ebias,
                                               int* __restrict__ topk_e,
                                               float* __restrict__ topk_w) {
  int wave = threadIdx.x >> 6, lane = threadIdx.x & 63;
  int t = blockIdx.x * 4 + wave;
  const float* xr = x + (size_t)t * H_DIM;
  float acc[E_NUM];
#pragma unroll
  for (int e = 0; e < E_NUM; ++e) acc[e] = 0.f;
  for (int h0 = lane * 4; h0 < H_DIM; h0 += 256) {
    float4 xv = *(const float4*)(xr + h0);
    float xs[4] = {xv.x, xv.y, xv.z, xv.w};
#pragma unroll
    for (int j = 0; j < 4; ++j) {
      const float4* gr = (const float4*)(gate + (size_t)(h0 + j) * E_NUM);
      float4 g0 = gr[0], g1 = gr[1], g2 = gr[2], g3 = gr[3];
      float s = xs[j];
      acc[0] += s * g0.x;  acc[1] += s * g0.y;  acc[2] += s * g0.z;  acc[3] += s * g0.w;
      acc[4] += s * g1.x;  acc[5] += s * g1.y;  acc[6] += s * g1.z;  acc[7] += s * g1.w;
      acc[8] += s * g2.x;  acc[9] += s * g2.y;  acc[10] += s * g2.z; acc[11] += s * g2.w;
      acc[12] += s * g3.x; acc[13] += s * g3.y; acc[14] += s * g3.z; acc[15] += s * g3.w;
    }
  }
#pragma unroll
  for (int s = 1; s < 64; s <<= 1) {
#pragma unroll
    for (int e = 0; e < E_NUM; ++e) acc[e] += __shfl_xor(acc[e], s, 64);
  }
  float score[E_NUM], sfc[E_NUM];
#pragma unroll
  for (int e = 0; e < E_NUM; ++e) {
    score[e] = 1.f / (1.f + expf(-acc[e]));
    sfc[e] = score[e] + ebias[e];
  }
  float gs[4];
#pragma unroll
  for (int g = 0; g < 4; ++g) {
    float a = sfc[4 * g], b = sfc[4 * g + 1], c = sfc[4 * g + 2], d = sfc[4 * g + 3];
    float p = fmaxf(a, b), q = fminf(a, b), r2 = fmaxf(c, d), s2 = fminf(c, d);
    gs[g] = fmaxf(p, r2) + fmaxf(fminf(p, r2), fmaxf(q, s2));
  }
  int g1 = 0; float b1 = gs[0];
#pragma unroll
  for (int g = 1; g < 4; ++g) if (gs[g] > b1) { b1 = gs[g]; g1 = g; }
  int g2 = -1; float b2 = -1e30f;
#pragma unroll
  for (int g = 0; g < 4; ++g) {
    bool ok = (g != g1) && (gs[g] > b2);
    b2 = ok ? gs[g] : b2; g2 = ok ? g : g2;
  }
  unsigned sel = 0; int idx[4]; float w[4];
#pragma unroll
  for (int k = 0; k < 4; ++k) {
    float best = -1e30f; int bi = 0; float bw = 0.f;
#pragma unroll
    for (int ee = 0; ee < 16; ++ee) {
      int grp = ee >> 2;
      float v = (grp == g1 || grp == g2) ? sfc[ee] : 0.0f;
      bool ok = (((sel >> ee) & 1u) == 0u) && (v > best);
      best = ok ? v : best; bi = ok ? ee : bi; bw = ok ? score[ee] : bw;
    }
    sel |= (1u << bi); idx[k] = bi; w[k] = bw;
  }
  float sum = w[0] + w[1] + w[2] + w[3];
  float sc = 2.5f / (sum + 1e-20f);
  if (lane == 0) {
#pragma unroll
    for (int k = 0; k < 4; ++k) {
      topk_e[t * 4 + k] = idx[k];
      topk_w[t * 4 + k] = w[k] * sc;
    }
  }
}

// ------------------------------------- histogram + prefix + scatter (1 block)
__global__ __launch_bounds__(256) void k_sort(const int* __restrict__ topk_e,
                                              const float* __restrict__ topk_w,
                                              int* __restrict__ offsets,
                                              int* __restrict__ row_token,
                                              float* __restrict__ row_w) {
  __shared__ int bins[E_NUM];
  __shared__ int base[E_NUM + 1];
  int tid = threadIdx.x;
  if (tid < E_NUM) bins[tid] = 0;
  __syncthreads();
  for (int i = tid; i < T_TOK * 4; i += 256) atomicAdd(&bins[topk_e[i]], 1);
  __syncthreads();
  if (tid == 0) {
    int s = 0;
    for (int k = 0; k < E_NUM; ++k) { base[k] = s; s += bins[k]; }
    base[E_NUM] = s;
  }
  __syncthreads();
  if (tid < E_NUM + 1) offsets[tid] = base[tid];
  if (tid < E_NUM) bins[tid] = base[tid];  // reuse as cursors
  __syncthreads();
  for (int i = tid; i < T_TOK * 4; i += 256) {
    int ee = topk_e[i];
    int slot = atomicAdd(&bins[ee], 1);
    row_token[slot] = i >> 2;
    row_w[slot] = topk_w[i];
  }
}

// -------------------------------------------------------------------- GEMM1
// a_compact[slot][f] = silu(x.Wg)*(x.Wu)*w  (bf16), gathered rows per expert.
// 2-phase double-buffered pipeline: stage K-step t+1 while computing t.
// Grid: x=f-strip (8) so all m-blocks/experts of a strip share an XCD's L2.
__global__ __launch_bounds__(256) void k_gemm1(
    const unsigned short* __restrict__ xb,    // [T][H] bf16
    const unsigned short* __restrict__ WgT,   // [E][F][H] bf16 (K-contig)
    const unsigned short* __restrict__ WuT,   // [E][F][H]
    const int* __restrict__ offsets, const int* __restrict__ row_token,
    const float* __restrict__ row_w,
    unsigned short* __restrict__ a_out) {     // [4096][F]
  int e = blockIdx.z;
  int offe = offsets[e];
  int ne = offsets[e + 1] - offe;
  int m0 = blockIdx.y * 64;
  if (m0 >= ne) return;
  int f0 = blockIdx.x * 64;

  __shared__ __align__(16) unsigned short As[2][4096];
  __shared__ __align__(16) unsigned short Bg[2][4096];
  __shared__ __align__(16) unsigned short Bu[2][4096];

  int tid = threadIdx.x;
  int wave = tid >> 6, lane = tid & 63;
  int wm = wave >> 1, wn = wave & 1;

  // staging: wave stages chunks ci=wave*2+i (1KB each: 8 rows x 128B).
  // XOR-swizzled source so linear global_load_lds dest + swizzled ds_read works.
  const unsigned short *sA[2], *sG[2], *sU[2];
  int cio[2];
#pragma unroll
  for (int i = 0; i < 2; ++i) {
    int ci = wave * 2 + i;
    int r = ci * 8 + (lane >> 3);
    int sw = (lane & 7) ^ (r & 7);
    int slot = offe + m0 + r; if (slot > 4095) slot = 4095;
    int tok = row_token[slot];
    sA[i] = xb + (size_t)tok * H_DIM + sw * 8;
    sG[i] = WgT + ((size_t)e * F_DIM + f0 + r) * H_DIM + sw * 8;
    sU[i] = WuT + ((size_t)e * F_DIM + f0 + r) * H_DIM + sw * 8;
    cio[i] = ci * 512;
  }

  int offA[2][2], offB[2][2];
#pragma unroll
  for (int fm = 0; fm < 2; ++fm) {
    int row = wm * 32 + fm * 16 + (lane & 15);
#pragma unroll
    for (int kk = 0; kk < 2; ++kk)
      offA[fm][kk] = row * 64 + (((kk * 4 + (lane >> 4)) ^ (row & 7)) * 8);
  }
#pragma unroll
  for (int fn = 0; fn < 2; ++fn) {
    int row = wn * 32 + fn * 16 + (lane & 15);
#pragma unroll
    for (int kk = 0; kk < 2; ++kk)
      offB[fn][kk] = row * 64 + (((kk * 4 + (lane >> 4)) ^ (row & 7)) * 8);
  }

  fx4 ag[2][2] = {}; fx4 au[2][2] = {};

#define STAGE1(b, k0)                                                          \
  do {                                                                         \
    _Pragma("unroll") for (int i = 0; i < 2; ++i) {                            \
      GLOAD_LDS(sA[i] + (k0), &As[b][cio[i]]);                                 \
      GLOAD_LDS(sG[i] + (k0), &Bg[b][cio[i]]);                                 \
      GLOAD_LDS(sU[i] + (k0), &Bu[b][cio[i]]);                                 \
    }                                                                          \
  } while (0)

#define COMPUTE1(b)                                                            \
  do {                                                                         \
    _Pragma("unroll") for (int kk = 0; kk < 2; ++kk) {                         \
      s16x8 a0 = *(const s16x8*)(&As[b][0] + offA[0][kk]);                     \
      s16x8 a1 = *(const s16x8*)(&As[b][0] + offA[1][kk]);                     \
      s16x8 g0 = *(const s16x8*)(&Bg[b][0] + offB[0][kk]);                     \
      s16x8 g1 = *(const s16x8*)(&Bg[b][0] + offB[1][kk]);                     \
      s16x8 u0 = *(const s16x8*)(&Bu[b][0] + offB[0][kk]);                     \
      s16x8 u1 = *(const s16x8*)(&Bu[b][0] + offB[1][kk]);                     \
      MFMA16(ag[0][0], a0, g0); MFMA16(ag[0][1], a0, g1);                      \
      MFMA16(ag[1][0], a1, g0); MFMA16(ag[1][1], a1, g1);                      \
      MFMA16(au[0][0], a0, u0); MFMA16(au[0][1], a0, u1);                      \
      MFMA16(au[1][0], a1, u0); MFMA16(au[1][1], a1, u1);                      \
    }                                                                          \
  } while (0)

  STAGE1(0, 0);
  __syncthreads();  // drains vmcnt(0): buffer 0 complete for all waves
#pragma unroll
  for (int t = 0; t < 15; ++t) {
    int cur = t & 1;
    STAGE1(cur ^ 1, (t + 1) * 64);   // overlap next-tile loads with compute
    COMPUTE1(cur);
    __syncthreads();  // vmcnt(0)+barrier: next buffer ready, cur free to reuse
  }
  COMPUTE1(1);  // t=15: buffer 15&1 = 1

#pragma unroll
  for (int fm = 0; fm < 2; ++fm) {
#pragma unroll
    for (int r = 0; r < 4; ++r) {
      int m = wm * 32 + fm * 16 + (lane >> 4) * 4 + r;
      bool ok = (m0 + m) < ne;
      int slot = offe + m0 + m;
      float w = ok ? row_w[slot] : 0.f;
#pragma unroll
      for (int fn = 0; fn < 2; ++fn) {
        int n = f0 + wn * 32 + fn * 16 + (lane & 15);
        float g = ag[fm][fn][r], u = au[fm][fn][r];
        float a = g / (1.f + __expf(-g)) * u * w;
        if (ok) a_out[(size_t)slot * F_DIM + n] = f2bf(a);
      }
    }
  }
#undef STAGE1
#undef COMPUTE1
}

// -------------------------------------------------------------------- GEMM2
// out[tok][h] += a_compact[slot] . WdT[e][h][:]   (atomicAdd combine)
// Same 2-phase pipeline; grid x=h-strip (16) for XCD locality.
__global__ __launch_bounds__(256) void k_gemm2(
    const unsigned short* __restrict__ a_in,  // [4096][F] bf16
    const unsigned short* __restrict__ WdT,   // [E][H][F] bf16 (K-contig)
    const int* __restrict__ offsets, const int* __restrict__ row_token,
    float* __restrict__ out) {                // [T][H] f32 (pre-zeroed)
  int e = blockIdx.z;
  int offe = offsets[e];
  int ne = offsets[e + 1] - offe;
  int m0 = blockIdx.y * 64;
  if (m0 >= ne) return;
  int h0 = blockIdx.x * 64;

  __shared__ __align__(16) unsigned short As[2][4096];
  __shared__ __align__(16) unsigned short Bd[2][4096];

  int tid = threadIdx.x;
  int wave = tid >> 6, lane = tid & 63;
  int wm = wave >> 1, wn = wave & 1;

  const unsigned short *sA[2], *sB[2];
  int cio[2];
#pragma unroll
  for (int i = 0; i < 2; ++i) {
    int ci = wave * 2 + i;
    int r = ci * 8 + (lane >> 3);
    int sw = (lane & 7) ^ (r & 7);
    int slot = offe + m0 + r; if (slot > 4095) slot = 4095;
    sA[i] = a_in + (size_t)slot * F_DIM + sw * 8;
    sB[i] = WdT + ((size_t)e * H_DIM + h0 + r) * F_DIM + sw * 8;
    cio[i] = ci * 512;
  }

  int offA[2][2], offB[2][2];
#pragma unroll
  for (int fm = 0; fm < 2; ++fm) {
    int row = wm * 32 + fm * 16 + (lane & 15);
#pragma unroll
    for (int kk = 0; kk < 2; ++kk)
      offA[fm][kk] = row * 64 + (((kk * 4 + (lane >> 4)) ^ (row & 7)) * 8);
  }
#pragma unroll
  for (int fn = 0; fn < 2; ++fn) {
    int row = wn * 32 + fn * 16 + (lane & 15);
#pragma unroll
    for (int kk = 0; kk < 2; ++kk)
      offB[fn][kk] = row * 64 + (((kk * 4 + (lane >> 4)) ^ (row & 7)) * 8);
  }

  fx4 acc[2][2] = {};

#define STAGE2(b, k0)                                                          \
  do {                                                                         \
    _Pragma("unroll") for (int i = 0; i < 2; ++i) {                            \
      GLOAD_LDS(sA[i] + (k0), &As[b][cio[i]]);                                 \
      GLOAD_LDS(sB[i] + (k0), &Bd[b][cio[i]]);                                 \
    }                                                                          \
  } while (0)

#define COMPUTE2(b)                                                            \
  do {                                                                         \
    _Pragma("unroll") for (int kk = 0; kk < 2; ++kk) {                         \
      s16x8 a0 = *(const s16x8*)(&As[b][0] + offA[0][kk]);                     \
      s16x8 a1 = *(const s16x8*)(&As[b][0] + offA[1][kk]);                     \
      s16x8 b0 = *(const s16x8*)(&Bd[b][0] + offB[0][kk]);                     \
      s16x8 b1 = *(const s16x8*)(&Bd[b][0] + offB[1][kk]);                     \
      MFMA16(acc[0][0], a0, b0); MFMA16(acc[0][1], a0, b1);                    \
      MFMA16(acc[1][0], a1, b0); MFMA16(acc[1][1], a1, b1);                    \
    }                                                                          \
  } while (0)

  STAGE2(0, 0);
  __syncthreads();
#pragma unroll
  for (int t = 0; t < 7; ++t) {
    int cur = t & 1;
    STAGE2(cur ^ 1, (t + 1) * 64);
    COMPUTE2(cur);
    __syncthreads();
  }
  COMPUTE2(1);  // t=7: buffer 7&1 = 1

#pragma unroll
  for (int fm = 0; fm < 2; ++fm) {
#pragma unroll
    for (int r = 0; r < 4; ++r) {
      int m = wm * 32 + fm * 16 + (lane >> 4) * 4 + r;
      bool ok = (m0 + m) < ne;
      int slot = offe + m0 + m; if (slot > 4095) slot = 4095;
      int tok = row_token[slot];
#pragma unroll
      for (int fn = 0; fn < 2; ++fn) {
        int n = h0 + wn * 32 + fn * 16 + (lane & 15);
        if (ok) atomicAdd(out + (size_t)tok * H_DIM + n, acc[fm][fn][r]);
      }
    }
  }
#undef STAGE2
#undef COMPUTE2
}

// ------------------------------------------------------------------- launch
extern "C" void kernel_launch(void* const* d_in, const int* in_sizes, int n_in,
                              void* d_out, int out_size, void* d_ws, size_t ws_size,
                              hipStream_t stream) {
  (void)in_sizes; (void)n_in; (void)out_size; (void)ws_size;
  const float* x    = (const float*)d_in[0];
  const float* gate = (const float*)d_in[1];
  const float* eb   = (const float*)d_in[2];
  const float* Wg   = (const float*)d_in[3];
  const float* Wu   = (const float*)d_in[4];
  const float* Wd   = (const float*)d_in[5];
  float* out = (float*)d_out;
  char* ws = (char*)d_ws;

  int*   offsets = (int*)(ws + 512);
  int*   topk_e  = (int*)(ws + 4096);
  float* topk_w  = (float*)(ws + 4096 + 16384);
  int*   row_tok = (int*)(ws + 4096 + 2 * 16384);
  float* row_w   = (float*)(ws + 4096 + 3 * 16384);
  unsigned short* xb  = (unsigned short*)(ws + (size_t)(1u << 20));        // 2 MB
  unsigned short* ac  = (unsigned short*)(ws + (size_t)3 * (1u << 20));    // 4 MB
  unsigned short* WgT = (unsigned short*)(ws + (size_t)16 * (1u << 20));   // 16 MB
  unsigned short* WuT = (unsigned short*)(ws + (size_t)32 * (1u << 20));   // 16 MB
  unsigned short* WdT = (unsigned short*)(ws + (size_t)48 * (1u << 20));   // 16 MB

  hipMemsetAsync(d_out, 0, (size_t)T_TOK * H_DIM * sizeof(float), stream);
  k_cvt_x<<<1024, 256, 0, stream>>>(x, xb, (T_TOK * H_DIM) / 4);
  k_trans<<<dim3(F_DIM / 64, H_DIM / 64, E_NUM), 256, 0, stream>>>(Wg, WgT, H_DIM, F_DIM);
  k_trans<<<dim3(F_DIM / 64, H_DIM / 64, E_NUM), 256, 0, stream>>>(Wu, WuT, H_DIM, F_DIM);
  k_trans<<<dim3(H_DIM / 64, F_DIM / 64, E_NUM), 256, 0, stream>>>(Wd, WdT, F_DIM, H_DIM);
  k_route<<<T_TOK / 4, 256, 0, stream>>>(x, gate, eb, topk_e, topk_w);
  k_sort<<<1, 256, 0, stream>>>(topk_e, topk_w, offsets, row_tok, row_w);
  // grid.x = f/h strip so same-strip blocks (sharing weight panels) map to the
  // same XCD slot (linear%8); grid.y = m-blocks (most exit early).
  k_gemm1<<<dim3(F_DIM / 64, 16, E_NUM), 256, 0, stream>>>(xb, WgT, WuT, offsets, row_tok, row_w, ac);
  k_gemm2<<<dim3(H_DIM / 64, 16, E_NUM), 256, 0, stream>>>(ac, WdT, offsets, row_tok, out);
}

// Round 13
// 201.519 us; speedup vs baseline: 1.4992x; 1.1076x over previous
//
#include <hip/hip_runtime.h>
#include <hip/hip_bf16.h>

// Problem constants (fixed by reference): T=1024 tokens, H=1024, F=512, E=16,
// top-4 of 16 experts, group logic 4 groups of 4, scaling 2.5.
#define T_TOK 1024
#define H_DIM 1024
#define F_DIM 512
#define E_NUM 16

typedef short s16x8 __attribute__((ext_vector_type(8)));
typedef float fx4 __attribute__((ext_vector_type(4)));

__device__ __forceinline__ unsigned short f2bf(float f) {
  union { float f; unsigned u; } v; v.f = f;
  unsigned r = v.u + 0x7fffu + ((v.u >> 16) & 1u);
  return (unsigned short)(r >> 16);
}

// MFMA via inline asm: D(+=)A*B, 16x16x32 bf16. A: row=lane&15, k=(lane>>4)*8+j.
// B: col=lane&15, k=(lane>>4)*8+j. D: col=lane&15, row=(lane>>4)*4+r.
#define MFMA16(acc, a, b) \
  asm("v_mfma_f32_16x16x32_bf16 %0, %1, %2, %0" : "+v"(acc) : "v"(a), "v"(b))

#define GLOAD_LDS(gsrc, ldst)                                                  \
  __builtin_amdgcn_global_load_lds(                                            \
      (const __attribute__((address_space(1))) void*)(gsrc),                   \
      (__attribute__((address_space(3))) void*)(ldst), 16, 0, 0)

// ---------------------------------------------------------------- prep bodies
// transpose+convert one 64x64 tile: in [E][R][C] fp32 -> out [E][C][R] bf16
__device__ __forceinline__ void trans_tile(const float* __restrict__ in,
                                           unsigned short* __restrict__ out,
                                           int R, int C, int cdiv, int local,
                                           unsigned short (*tile)[72]) {
  int cb = local % cdiv;
  int rb = (local / cdiv) % (R >> 6);
  int e = local >> 7;  // 128 tile-blocks per expert for both shapes
  int c0 = cb * 64, r0 = rb * 64;
  const float* ip = in + (size_t)e * R * C;
  unsigned short* op = out + (size_t)e * R * C;
  int tid = threadIdx.x;
  int cq = (tid & 15) * 4;
  int rr = tid >> 4;  // 0..15
#pragma unroll
  for (int p = 0; p < 4; ++p) {
    int r = rr + p * 16;
    float4 v = *(const float4*)(ip + (size_t)(r0 + r) * C + c0 + cq);
    tile[cq + 0][r] = f2bf(v.x);
    tile[cq + 1][r] = f2bf(v.y);
    tile[cq + 2][r] = f2bf(v.z);
    tile[cq + 3][r] = f2bf(v.w);
  }
  __syncthreads();
  int cr = tid >> 2;          // 0..63 output row within tile
  int rc = (tid & 3) * 16;    // 16-elem chunk
  unsigned short* dst = op + (size_t)(c0 + cr) * R + r0 + rc;
  *(uint4*)(dst + 0) = *(const uint4*)&tile[cr][rc + 0];
  *(uint4*)(dst + 8) = *(const uint4*)&tile[cr][rc + 8];
}

// routing for 4 tokens (one wave each). No global atomics (round-2 lesson:
// 4096 atomics on one cache line = ~58us cross-XCD serialization).
__device__ __forceinline__ void route_body(const float* __restrict__ x,
                                           const float* __restrict__ gate,
                                           const float* __restrict__ ebias,
                                           int* __restrict__ topk_e,
                                           float* __restrict__ topk_w, int bid) {
  int wave = threadIdx.x >> 6, lane = threadIdx.x & 63;
  int t = bid * 4 + wave;
  const float* xr = x + (size_t)t * H_DIM;
  float acc[E_NUM];
#pragma unroll
  for (int e = 0; e < E_NUM; ++e) acc[e] = 0.f;
  for (int h0 = lane * 4; h0 < H_DIM; h0 += 256) {
    float4 xv = *(const float4*)(xr + h0);
    float xs[4] = {xv.x, xv.y, xv.z, xv.w};
#pragma unroll
    for (int j = 0; j < 4; ++j) {
      const float4* gr = (const float4*)(gate + (size_t)(h0 + j) * E_NUM);
      float4 g0 = gr[0], g1 = gr[1], g2 = gr[2], g3 = gr[3];
      float s = xs[j];
      acc[0] += s * g0.x;  acc[1] += s * g0.y;  acc[2] += s * g0.z;  acc[3] += s * g0.w;
      acc[4] += s * g1.x;  acc[5] += s * g1.y;  acc[6] += s * g1.z;  acc[7] += s * g1.w;
      acc[8] += s * g2.x;  acc[9] += s * g2.y;  acc[10] += s * g2.z; acc[11] += s * g2.w;
      acc[12] += s * g3.x; acc[13] += s * g3.y; acc[14] += s * g3.z; acc[15] += s * g3.w;
    }
  }
#pragma unroll
  for (int s = 1; s < 64; s <<= 1) {
#pragma unroll
    for (int e = 0; e < E_NUM; ++e) acc[e] += __shfl_xor(acc[e], s, 64);
  }
  float score[E_NUM], sfc[E_NUM];
#pragma unroll
  for (int e = 0; e < E_NUM; ++e) {
    score[e] = 1.f / (1.f + expf(-acc[e]));
    sfc[e] = score[e] + ebias[e];
  }
  float gs[4];
#pragma unroll
  for (int g = 0; g < 4; ++g) {
    float a = sfc[4 * g], b = sfc[4 * g + 1], c = sfc[4 * g + 2], d = sfc[4 * g + 3];
    float p = fmaxf(a, b), q = fminf(a, b), r2 = fmaxf(c, d), s2 = fminf(c, d);
    gs[g] = fmaxf(p, r2) + fmaxf(fminf(p, r2), fmaxf(q, s2));
  }
  int g1 = 0; float b1 = gs[0];
#pragma unroll
  for (int g = 1; g < 4; ++g) if (gs[g] > b1) { b1 = gs[g]; g1 = g; }
  int g2 = -1; float b2 = -1e30f;
#pragma unroll
  for (int g = 0; g < 4; ++g) {
    bool ok = (g != g1) && (gs[g] > b2);
    b2 = ok ? gs[g] : b2; g2 = ok ? g : g2;
  }
  unsigned sel = 0; int idx[4]; float w[4];
#pragma unroll
  for (int k = 0; k < 4; ++k) {
    float best = -1e30f; int bi = 0; float bw = 0.f;
#pragma unroll
    for (int ee = 0; ee < 16; ++ee) {
      int grp = ee >> 2;
      float v = (grp == g1 || grp == g2) ? sfc[ee] : 0.0f;
      bool ok = (((sel >> ee) & 1u) == 0u) && (v > best);
      best = ok ? v : best; bi = ok ? ee : bi; bw = ok ? score[ee] : bw;
    }
    sel |= (1u << bi); idx[k] = bi; w[k] = bw;
  }
  float sum = w[0] + w[1] + w[2] + w[3];
  float sc = 2.5f / (sum + 1e-20f);
  if (lane == 0) {
#pragma unroll
    for (int k = 0; k < 4; ++k) {
      topk_e[t * 4 + k] = idx[k];
      topk_w[t * 4 + k] = w[k] * sc;
    }
  }
}

// --------------------------------------------------------- fused prep kernel
// Flat block ranges (route first: latency-bound, hides under BW-bound trans):
//   [0,256)      route (4 tokens/block)
//   [256,384)    x fp32->bf16 (128 blocks)
//   [384,512)    zero d_out  (128 blocks)
//   [512,2560)   trans W_gate  (2048)
//   [2560,4608)  trans W_up    (2048)
//   [4608,6656)  trans W_down  (2048)
__global__ __launch_bounds__(256) void k_prep(
    const float* __restrict__ x, const float* __restrict__ gate,
    const float* __restrict__ ebias,
    const float* __restrict__ Wg, const float* __restrict__ Wu,
    const float* __restrict__ Wd,
    unsigned short* __restrict__ xb, unsigned short* __restrict__ WgT,
    unsigned short* __restrict__ WuT, unsigned short* __restrict__ WdT,
    float* __restrict__ out_zero,
    int* __restrict__ topk_e, float* __restrict__ topk_w) {
  __shared__ unsigned short tile[64][72];
  int id = blockIdx.x;
  if (id < 256) {
    route_body(x, gate, ebias, topk_e, topk_w, id);
  } else if (id < 384) {
    int b = id - 256;
    const int n4 = (T_TOK * H_DIM) / 4;
    for (int i = b * 256 + (int)threadIdx.x; i < n4; i += 128 * 256) {
      float4 v = ((const float4*)x)[i];
      ushort4 o;
      o.x = f2bf(v.x); o.y = f2bf(v.y); o.z = f2bf(v.z); o.w = f2bf(v.w);
      ((ushort4*)xb)[i] = o;
    }
  } else if (id < 512) {
    int b = id - 384;
    const int n4 = (T_TOK * H_DIM) / 4;
    float4 z = make_float4(0.f, 0.f, 0.f, 0.f);
    for (int i = b * 256 + (int)threadIdx.x; i < n4; i += 128 * 256)
      ((float4*)out_zero)[i] = z;
  } else if (id < 2560) {
    trans_tile(Wg, WgT, H_DIM, F_DIM, 8, id - 512, tile);
  } else if (id < 4608) {
    trans_tile(Wu, WuT, H_DIM, F_DIM, 8, id - 2560, tile);
  } else {
    trans_tile(Wd, WdT, F_DIM, H_DIM, 16, id - 4608, tile);
  }
}

// ------------------------------------- histogram + prefix + scatter (1 block)
__global__ __launch_bounds__(256) void k_sort(const int* __restrict__ topk_e,
                                              const float* __restrict__ topk_w,
                                              int* __restrict__ offsets,
                                              int* __restrict__ row_token,
                                              float* __restrict__ row_w) {
  __shared__ int bins[E_NUM];
  __shared__ int base[E_NUM + 1];
  int tid = threadIdx.x;
  if (tid < E_NUM) bins[tid] = 0;
  __syncthreads();
  for (int i = tid; i < T_TOK * 4; i += 256) atomicAdd(&bins[topk_e[i]], 1);
  __syncthreads();
  if (tid == 0) {
    int s = 0;
    for (int k = 0; k < E_NUM; ++k) { base[k] = s; s += bins[k]; }
    base[E_NUM] = s;
  }
  __syncthreads();
  if (tid < E_NUM + 1) offsets[tid] = base[tid];
  if (tid < E_NUM) bins[tid] = base[tid];  // reuse as cursors
  __syncthreads();
  for (int i = tid; i < T_TOK * 4; i += 256) {
    int ee = topk_e[i];
    int slot = atomicAdd(&bins[ee], 1);
    row_token[slot] = i >> 2;
    row_w[slot] = topk_w[i];
  }
}

// -------------------------------------------------------------------- GEMM1
// a_compact[slot][f] = silu(x.Wg)*(x.Wu)*w  (bf16), gathered rows per expert.
// 2-phase double-buffered pipeline: stage K-step t+1 while computing t.
// Grid: x=f-strip (8) so all m-blocks/experts of a strip share an XCD's L2.
__global__ __launch_bounds__(256) void k_gemm1(
    const unsigned short* __restrict__ xb,    // [T][H] bf16
    const unsigned short* __restrict__ WgT,   // [E][F][H] bf16 (K-contig)
    const unsigned short* __restrict__ WuT,   // [E][F][H]
    const int* __restrict__ offsets, const int* __restrict__ row_token,
    const float* __restrict__ row_w,
    unsigned short* __restrict__ a_out) {     // [4096][F]
  int e = blockIdx.z;
  int offe = offsets[e];
  int ne = offsets[e + 1] - offe;
  int m0 = blockIdx.y * 64;
  if (m0 >= ne) return;
  int f0 = blockIdx.x * 64;

  __shared__ __align__(16) unsigned short As[2][4096];
  __shared__ __align__(16) unsigned short Bg[2][4096];
  __shared__ __align__(16) unsigned short Bu[2][4096];

  int tid = threadIdx.x;
  int wave = tid >> 6, lane = tid & 63;
  int wm = wave >> 1, wn = wave & 1;

  // staging: wave stages chunks ci=wave*2+i (1KB each: 8 rows x 128B).
  // XOR-swizzled source so linear global_load_lds dest + swizzled ds_read works.
  const unsigned short *sA[2], *sG[2], *sU[2];
  int cio[2];
#pragma unroll
  for (int i = 0; i < 2; ++i) {
    int ci = wave * 2 + i;
    int r = ci * 8 + (lane >> 3);
    int sw = (lane & 7) ^ (r & 7);
    int slot = offe + m0 + r; if (slot > 4095) slot = 4095;
    int tok = row_token[slot];
    sA[i] = xb + (size_t)tok * H_DIM + sw * 8;
    sG[i] = WgT + ((size_t)e * F_DIM + f0 + r) * H_DIM + sw * 8;
    sU[i] = WuT + ((size_t)e * F_DIM + f0 + r) * H_DIM + sw * 8;
    cio[i] = ci * 512;
  }

  int offA[2][2], offB[2][2];
#pragma unroll
  for (int fm = 0; fm < 2; ++fm) {
    int row = wm * 32 + fm * 16 + (lane & 15);
#pragma unroll
    for (int kk = 0; kk < 2; ++kk)
      offA[fm][kk] = row * 64 + (((kk * 4 + (lane >> 4)) ^ (row & 7)) * 8);
  }
#pragma unroll
  for (int fn = 0; fn < 2; ++fn) {
    int row = wn * 32 + fn * 16 + (lane & 15);
#pragma unroll
    for (int kk = 0; kk < 2; ++kk)
      offB[fn][kk] = row * 64 + (((kk * 4 + (lane >> 4)) ^ (row & 7)) * 8);
  }

  fx4 ag[2][2] = {}; fx4 au[2][2] = {};

#define STAGE1(b, k0)                                                          \
  do {                                                                         \
    _Pragma("unroll") for (int i = 0; i < 2; ++i) {                            \
      GLOAD_LDS(sA[i] + (k0), &As[b][cio[i]]);                                 \
      GLOAD_LDS(sG[i] + (k0), &Bg[b][cio[i]]);                                 \
      GLOAD_LDS(sU[i] + (k0), &Bu[b][cio[i]]);                                 \
    }                                                                          \
  } while (0)

#define COMPUTE1(b)                                                            \
  do {                                                                         \
    _Pragma("unroll") for (int kk = 0; kk < 2; ++kk) {                         \
      s16x8 a0 = *(const s16x8*)(&As[b][0] + offA[0][kk]);                     \
      s16x8 a1 = *(const s16x8*)(&As[b][0] + offA[1][kk]);                     \
      s16x8 g0 = *(const s16x8*)(&Bg[b][0] + offB[0][kk]);                     \
      s16x8 g1 = *(const s16x8*)(&Bg[b][0] + offB[1][kk]);                     \
      s16x8 u0 = *(const s16x8*)(&Bu[b][0] + offB[0][kk]);                     \
      s16x8 u1 = *(const s16x8*)(&Bu[b][0] + offB[1][kk]);                     \
      MFMA16(ag[0][0], a0, g0); MFMA16(ag[0][1], a0, g1);                      \
      MFMA16(ag[1][0], a1, g0); MFMA16(ag[1][1], a1, g1);                      \
      MFMA16(au[0][0], a0, u0); MFMA16(au[0][1], a0, u1);                      \
      MFMA16(au[1][0], a1, u0); MFMA16(au[1][1], a1, u1);                      \
    }                                                                          \
  } while (0)

  STAGE1(0, 0);
  __syncthreads();  // drains vmcnt(0): buffer 0 complete for all waves
#pragma unroll
  for (int t = 0; t < 15; ++t) {
    int cur = t & 1;
    STAGE1(cur ^ 1, (t + 1) * 64);   // overlap next-tile loads with compute
    COMPUTE1(cur);
    __syncthreads();  // vmcnt(0)+barrier: next buffer ready, cur free to reuse
  }
  COMPUTE1(1);  // t=15: buffer 15&1 = 1

#pragma unroll
  for (int fm = 0; fm < 2; ++fm) {
#pragma unroll
    for (int r = 0; r < 4; ++r) {
      int m = wm * 32 + fm * 16 + (lane >> 4) * 4 + r;
      bool ok = (m0 + m) < ne;
      int slot = offe + m0 + m;
      float w = ok ? row_w[slot] : 0.f;
#pragma unroll
      for (int fn = 0; fn < 2; ++fn) {
        int n = f0 + wn * 32 + fn * 16 + (lane & 15);
        float g = ag[fm][fn][r], u = au[fm][fn][r];
        float a = g / (1.f + __expf(-g)) * u * w;
        if (ok) a_out[(size_t)slot * F_DIM + n] = f2bf(a);
      }
    }
  }
#undef STAGE1
#undef COMPUTE1
}

// -------------------------------------------------------------------- GEMM2
// out[tok][h] += a_compact[slot] . WdT[e][h][:]   (atomicAdd combine)
// Same 2-phase pipeline; grid x=h-strip (16) for XCD locality.
__global__ __launch_bounds__(256) void k_gemm2(
    const unsigned short* __restrict__ a_in,  // [4096][F] bf16
    const unsigned short* __restrict__ WdT,   // [E][H][F] bf16 (K-contig)
    const int* __restrict__ offsets, const int* __restrict__ row_token,
    float* __restrict__ out) {                // [T][H] f32 (pre-zeroed)
  int e = blockIdx.z;
  int offe = offsets[e];
  int ne = offsets[e + 1] - offe;
  int m0 = blockIdx.y * 64;
  if (m0 >= ne) return;
  int h0 = blockIdx.x * 64;

  __shared__ __align__(16) unsigned short As[2][4096];
  __shared__ __align__(16) unsigned short Bd[2][4096];

  int tid = threadIdx.x;
  int wave = tid >> 6, lane = tid & 63;
  int wm = wave >> 1, wn = wave & 1;

  const unsigned short *sA[2], *sB[2];
  int cio[2];
#pragma unroll
  for (int i = 0; i < 2; ++i) {
    int ci = wave * 2 + i;
    int r = ci * 8 + (lane >> 3);
    int sw = (lane & 7) ^ (r & 7);
    int slot = offe + m0 + r; if (slot > 4095) slot = 4095;
    sA[i] = a_in + (size_t)slot * F_DIM + sw * 8;
    sB[i] = WdT + ((size_t)e * H_DIM + h0 + r) * F_DIM + sw * 8;
    cio[i] = ci * 512;
  }

  int offA[2][2], offB[2][2];
#pragma unroll
  for (int fm = 0; fm < 2; ++fm) {
    int row = wm * 32 + fm * 16 + (lane & 15);
#pragma unroll
    for (int kk = 0; kk < 2; ++kk)
      offA[fm][kk] = row * 64 + (((kk * 4 + (lane >> 4)) ^ (row & 7)) * 8);
  }
#pragma unroll
  for (int fn = 0; fn < 2; ++fn) {
    int row = wn * 32 + fn * 16 + (lane & 15);
#pragma unroll
    for (int kk = 0; kk < 2; ++kk)
      offB[fn][kk] = row * 64 + (((kk * 4 + (lane >> 4)) ^ (row & 7)) * 8);
  }

  fx4 acc[2][2] = {};

#define STAGE2(b, k0)                                                          \
  do {                                                                         \
    _Pragma("unroll") for (int i = 0; i < 2; ++i) {                            \
      GLOAD_LDS(sA[i] + (k0), &As[b][cio[i]]);                                 \
      GLOAD_LDS(sB[i] + (k0), &Bd[b][cio[i]]);                                 \
    }                                                                          \
  } while (0)

#define COMPUTE2(b)                                                            \
  do {                                                                         \
    _Pragma("unroll") for (int kk = 0; kk < 2; ++kk) {                         \
      s16x8 a0 = *(const s16x8*)(&As[b][0] + offA[0][kk]);                     \
      s16x8 a1 = *(const s16x8*)(&As[b][0] + offA[1][kk]);                     \
      s16x8 b0 = *(const s16x8*)(&Bd[b][0] + offB[0][kk]);                     \
      s16x8 b1 = *(const s16x8*)(&Bd[b][0] + offB[1][kk]);                     \
      MFMA16(acc[0][0], a0, b0); MFMA16(acc[0][1], a0, b1);                    \
      MFMA16(acc[1][0], a1, b0); MFMA16(acc[1][1], a1, b1);                    \
    }                                                                          \
  } while (0)

  STAGE2(0, 0);
  __syncthreads();
#pragma unroll
  for (int t = 0; t < 7; ++t) {
    int cur = t & 1;
    STAGE2(cur ^ 1, (t + 1) * 64);
    COMPUTE2(cur);
    __syncthreads();
  }
  COMPUTE2(1);  // t=7: buffer 7&1 = 1

#pragma unroll
  for (int fm = 0; fm < 2; ++fm) {
#pragma unroll
    for (int r = 0; r < 4; ++r) {
      int m = wm * 32 + fm * 16 + (lane >> 4) * 4 + r;
      bool ok = (m0 + m) < ne;
      int slot = offe + m0 + m; if (slot > 4095) slot = 4095;
      int tok = row_token[slot];
#pragma unroll
      for (int fn = 0; fn < 2; ++fn) {
        int n = h0 + wn * 32 + fn * 16 + (lane & 15);
        if (ok) atomicAdd(out + (size_t)tok * H_DIM + n, acc[fm][fn][r]);
      }
    }
  }
#undef STAGE2
#undef COMPUTE2
}

// ------------------------------------------------------------------- launch
extern "C" void kernel_launch(void* const* d_in, const int* in_sizes, int n_in,
                              void* d_out, int out_size, void* d_ws, size_t ws_size,
                              hipStream_t stream) {
  (void)in_sizes; (void)n_in; (void)out_size; (void)ws_size;
  const float* x    = (const float*)d_in[0];
  const float* gate = (const float*)d_in[1];
  const float* eb   = (const float*)d_in[2];
  const float* Wg   = (const float*)d_in[3];
  const float* Wu   = (const float*)d_in[4];
  const float* Wd   = (const float*)d_in[5];
  float* out = (float*)d_out;
  char* ws = (char*)d_ws;

  int*   offsets = (int*)(ws + 512);
  int*   topk_e  = (int*)(ws + 4096);
  float* topk_w  = (float*)(ws + 4096 + 16384);
  int*   row_tok = (int*)(ws + 4096 + 2 * 16384);
  float* row_w   = (float*)(ws + 4096 + 3 * 16384);
  unsigned short* xb  = (unsigned short*)(ws + (size_t)(1u << 20));        // 2 MB
  unsigned short* ac  = (unsigned short*)(ws + (size_t)3 * (1u << 20));    // 4 MB
  unsigned short* WgT = (unsigned short*)(ws + (size_t)16 * (1u << 20));   // 16 MB
  unsigned short* WuT = (unsigned short*)(ws + (size_t)32 * (1u << 20));   // 16 MB
  unsigned short* WdT = (unsigned short*)(ws + (size_t)48 * (1u << 20));   // 16 MB

  // One fused prep dispatch: route + x-convert + out-zero + 3 transposes.
  k_prep<<<6656, 256, 0, stream>>>(x, gate, eb, Wg, Wu, Wd,
                                   xb, WgT, WuT, WdT, out, topk_e, topk_w);
  k_sort<<<1, 256, 0, stream>>>(topk_e, topk_w, offsets, row_tok, row_w);
  // grid.x = f/h strip so same-strip blocks (sharing weight panels) map to the
  // same XCD slot (linear%8); grid.y = m-blocks (most exit early).
  k_gemm1<<<dim3(F_DIM / 64, 16, E_NUM), 256, 0, stream>>>(xb, WgT, WuT, offsets, row_tok, row_w, ac);
  k_gemm2<<<dim3(H_DIM / 64, 16, E_NUM), 256, 0, stream>>>(ac, WdT, offsets, row_tok, out);
}